// Round 14
// baseline (67.294 us; speedup 1.0000x reference)
//
#include <hip/hip_runtime.h>
#include <hip/hip_bf16.h>
#include <math.h>

#define B_   32
#define N_   8192
#define H_   128
#define G_   10
#define TOKS (B_*N_)
#define THREADS 512
#define WAVES 8
#define NITER 4
#define TPB 1024   // 8 waves x 32 tok/tile x 4 tiles -> grid = exactly 256 blocks (1/CU)
#define LDW 136    // W1 row stride in shorts (272B)

typedef short bf16x8 __attribute__((ext_vector_type(8)));
typedef short bf16x4 __attribute__((ext_vector_type(4)));
typedef float f32x4 __attribute__((ext_vector_type(4)));

// ws image layout (shorts):
//   w1s [3][128][136]        W1^T padded           (52224 shorts)
//   w2f [3][8][64][4]        W2^T lane-major frags (6144 shorts)
//   b1 [3][128] f32, b2 [3][16] f32
#define WS_IMG_OFF 256
#define IMG_W2   (3*H_*LDW)            // 52224
#define IMG_BF   (IMG_W2 + 3*8*64*4)   // 58368
#define IMG_BYTES (IMG_BF*2 + 3*H_*4 + 3*16*4)   // 118464
#define IMG_INSTS 116                  // ceil(118464/1024); overshoot 320B -> red/pad (safe)

struct __align__(16) SMem {
  short w1s[3][H_][LDW];     // W1^T bf16: [head][hidden j][input i]
  short w2f[3][8][64][4];    // W2^T K16 A-frags, lane-major: conflict-free b64
  float b1s[3][H_];
  float b2s[3][16];
  float red[WAVES][3];       // staging overshoot lands here; written post-compute
  char  pad[640];
};

__device__ __forceinline__ short f2bf(float f) {
  __hip_bfloat16 h = __float2bfloat16(f);
  union { __hip_bfloat16 h; short s; } u; u.h = h;
  return u.s;
}

__device__ __forceinline__ void async_copy16(void* lds_uniform, const void* gsrc_perlane) {
  __builtin_amdgcn_global_load_lds(
      (const __attribute__((address_space(1))) unsigned int*)gsrc_perlane,
      (__attribute__((address_space(3))) unsigned int*)lds_uniform,
      16, 0, 0);
}

__global__ __launch_bounds__(64) void init_kernel(float* out, float* ws) {
  int t = threadIdx.x;
  if (t < 33) out[t] = 0.0f;
  if (t < 2)  ws[t]  = 0.0f;
}

__global__ __launch_bounds__(64) void fin_kernel(float* out, const float* ws) {
  if (threadIdx.x == 0) out[32] = ws[0] / fmaxf(ws[1], 1.0f);
}

__global__ __launch_bounds__(256) void prep_kernel(
    const float* __restrict__ w1_0, const float* __restrict__ b1_0,
    const float* __restrict__ w2_0, const float* __restrict__ b2_0,
    const float* __restrict__ w1_1, const float* __restrict__ b1_1,
    const float* __restrict__ w2_1, const float* __restrict__ b2_1,
    const float* __restrict__ w1_2, const float* __restrict__ b1_2,
    const float* __restrict__ w2_2, const float* __restrict__ b2_2,
    short* __restrict__ img) {
  const float* w1p[3] = {w1_0, w1_1, w1_2};
  const float* w2p[3] = {w2_0, w2_1, w2_2};
  const float* b1p[3] = {b1_0, b1_1, b1_2};
  const float* b2p[3] = {b2_0, b2_1, b2_2};
  int t = blockIdx.x * 256 + threadIdx.x;
  int stride = gridDim.x * 256;
  // W1^T padded
  for (int idx = t; idx < 3*H_*LDW; idx += stride) {
    int h = idx / (H_*LDW), rem = idx - h*(H_*LDW);
    int j = rem / LDW, i = rem - j*LDW;
    img[idx] = (i < H_) ? f2bf(w1p[h][i*H_ + j]) : (short)0;
  }
  // W2^T lane-major K16 fragments: w2f[h][nt][lane] holds W2^T[g=lane&15][k=nt*16+(lane>>4)*4+e]
  for (int idx = t; idx < 3*8*64; idx += stride) {
    int h = idx / 512, rem = idx - h*512;
    int nt = rem >> 6, ln = rem & 63;
    int qq = ln >> 4, lg = ln & 15;
#pragma unroll
    for (int e = 0; e < 4; ++e) {
      int k = nt*16 + qq*4 + e;
      img[IMG_W2 + idx*4 + e] = (lg < G_) ? f2bf(w2p[h][k*G_ + lg]) : (short)0;
    }
  }
  float* bimg = (float*)(img + IMG_BF);
  if (t < 3*H_ + 3*16) {
    if (t < 3*H_) { int h = t >> 7, j = t & 127; bimg[t] = b1p[h][j]; }
    else { int i2 = t - 3*H_; int h = i2 >> 4, g = i2 & 15;
           bimg[t] = (g < G_) ? b2p[h][g] : 0.0f; }
  }
}

template<int PREP>
__global__ __launch_bounds__(THREADS, 2)   // 256-reg cap
void rtm_main(const float* __restrict__ feat,
              const float* __restrict__ dist,
              const int* __restrict__ dmask,
              const float* __restrict__ img,
              const float* __restrict__ w1_0, const float* __restrict__ b1_0,
              const float* __restrict__ w2_0, const float* __restrict__ b2_0,
              const float* __restrict__ w1_1, const float* __restrict__ b1_1,
              const float* __restrict__ w2_1, const float* __restrict__ b2_1,
              const float* __restrict__ w1_2, const float* __restrict__ b1_2,
              const float* __restrict__ w2_2, const float* __restrict__ b2_2,
              float* __restrict__ out, float* __restrict__ ws) {
  __shared__ SMem sm;

  const int tid  = threadIdx.x;
  const int wave = tid >> 6;
  const int lane = tid & 63;
  const int q  = lane >> 4;
  const int lg = lane & 15;
  const long wbase = (long)blockIdx.x * TPB + (long)wave * (32*NITER);

  // ---- prologue: issue tile-0 loads ----
  float4 fv[2][8];
  float dpre[2]; int mpre[2];
#pragma unroll
  for (int mt = 0; mt < 2; ++mt) {
    const float* fr = feat + (wbase + mt*16 + lg) * (long)H_;
#pragma unroll
    for (int c = 0; c < 4; ++c) {
      const float4* p = reinterpret_cast<const float4*>(fr + c*32 + q*8);
      fv[mt][2*c]   = p[0];
      fv[mt][2*c+1] = p[1];
    }
    dpre[mt] = dist[wbase + mt*16 + lg];
    mpre[mt] = dmask[wbase + mt*16 + lg];
  }

  // ---- stage weight image to LDS (async; once per CU) ----
  if constexpr (PREP) {
    char* smb = (char*)&sm;
    const char* gimg = (const char*)img;
    for (int i = wave; i < IMG_INSTS; i += WAVES)
      async_copy16(smb + i*1024, gimg + i*1024 + lane*16);
  } else {
    const float* w1p[3] = {w1_0, w1_1, w1_2};
    const float* w2p[3] = {w2_0, w2_1, w2_2};
    const float* b1p[3] = {b1_0, b1_1, b1_2};
    const float* b2p[3] = {b2_0, b2_1, b2_2};
    for (int h = 0; h < 3; ++h) {
      for (int idx = tid; idx < H_*H_; idx += THREADS) {
        int i = idx >> 7, j = idx & 127;
        sm.w1s[h][j][i] = f2bf(w1p[h][idx]);
      }
      for (int idx = tid; idx < 8*64; idx += THREADS) {
        int nt = idx >> 6, ln = idx & 63;
        int qq = ln >> 4, lgg = ln & 15;
#pragma unroll
        for (int e = 0; e < 4; ++e) {
          int k = nt*16 + qq*4 + e;
          sm.w2f[h][nt][ln][e] = (lgg < G_) ? f2bf(w2p[h][k*G_ + lgg]) : (short)0;
        }
      }
      if (tid < H_) sm.b1s[h][tid] = b1p[h][tid];
      if (tid < 16) sm.b2s[h][tid] = (tid < G_) ? b2p[h][tid] : 0.0f;
    }
  }

  // ---- convert tile 0 while staging is in flight ----
  bf16x8 a1[2][4];   // B-frag (K=32): lane holds B[k=(lane>>4)*8+e][tok=lane&15]
#pragma unroll
  for (int mt = 0; mt < 2; ++mt)
#pragma unroll
    for (int c = 0; c < 4; ++c) {
      float4 lo = fv[mt][2*c], hi = fv[mt][2*c+1];
      bf16x8 a;
      a[0]=f2bf(lo.x); a[1]=f2bf(lo.y); a[2]=f2bf(lo.z); a[3]=f2bf(lo.w);
      a[4]=f2bf(hi.x); a[5]=f2bf(hi.y); a[6]=f2bf(hi.z); a[7]=f2bf(hi.w);
      a1[mt][c] = a;
    }

  __syncthreads();   // weights visible; drains global_load_lds

  float* out_score = out;
  float* out_pi = out + 33;
  float* out_mu = out + 33 + (size_t)TOKS*G_;
  float* out_sg = out + 33 + 2*(size_t)TOKS*G_;
  const float HLOG2PI = 0.91893853320467274f;
  const bool v0 = (q*4+0) < G_, v1 = (q*4+1) < G_, v2 = (q*4+2) < G_, v3 = (q*4+3) < G_;

  float accP = 0.f, accL = 0.f, accC = 0.f;

  // ---- pipelined tile loop ----
#pragma unroll
  for (int s = 0; s < NITER; ++s) {
    float dnx[2]; int mnx[2];
    if (s + 1 < NITER) {
#pragma unroll
      for (int mt = 0; mt < 2; ++mt) {
        const float* fr = feat + (wbase + (s+1)*32 + mt*16 + lg) * (long)H_;
#pragma unroll
        for (int c = 0; c < 4; ++c) {
          const float4* p = reinterpret_cast<const float4*>(fr + c*32 + q*8);
          fv[mt][2*c]   = p[0];
          fv[mt][2*c+1] = p[1];
        }
        dnx[mt] = dist[wbase + (s+1)*32 + mt*16 + lg];
        mnx[mt] = dmask[wbase + (s+1)*32 + mt*16 + lg];
      }
    }

    // ---- compute tile s ----
    f32x4 lgt[3][2];
#pragma unroll
    for (int h = 0; h < 3; ++h) {
      // W2^T K16 A-frags: lane-major, conflict-free ds_read_b64
      bf16x4 w2fr[8];
#pragma unroll
      for (int nt = 0; nt < 8; ++nt)
        w2fr[nt] = *reinterpret_cast<const bf16x4*>(sm.w2f[h][nt][lane]);

      f32x4 acc[2][8];
#pragma unroll
      for (int mt = 0; mt < 2; ++mt)
#pragma unroll
        for (int nt = 0; nt < 8; ++nt) acc[mt][nt] = (f32x4){0.f,0.f,0.f,0.f};
#pragma unroll
      for (int c = 0; c < 4; ++c) {
#pragma unroll
        for (int nt = 0; nt < 8; ++nt) {
          bf16x8 wfr = *reinterpret_cast<const bf16x8*>(&sm.w1s[h][nt*16 + lg][c*32 + q*8]);
          acc[0][nt] = __builtin_amdgcn_mfma_f32_16x16x32_bf16(wfr, a1[0][c], acc[0][nt], 0, 0, 0);
          acc[1][nt] = __builtin_amdgcn_mfma_f32_16x16x32_bf16(wfr, a1[1][c], acc[1][nt], 0, 0, 0);
        }
      }
#pragma unroll
      for (int mt = 0; mt < 2; ++mt) {
        // layer 2 in registers, two independent MFMA chains
        f32x4 lacc0 = (f32x4){0.f,0.f,0.f,0.f};
        f32x4 lacc1 = (f32x4){0.f,0.f,0.f,0.f};
#pragma unroll
        for (int nt = 0; nt < 8; ++nt) {
          f32x4 b1v = *reinterpret_cast<const f32x4*>(&sm.b1s[h][nt*16 + q*4]);
          bf16x4 pkv;
#pragma unroll
          for (int r = 0; r < 4; ++r)
            pkv[r] = f2bf(fmaxf(acc[mt][nt][r] + b1v[r], 0.0f));
          if (nt & 1)
            lacc1 = __builtin_amdgcn_mfma_f32_16x16x16bf16_1k(w2fr[nt], pkv, lacc1, 0, 0, 0);
          else
            lacc0 = __builtin_amdgcn_mfma_f32_16x16x16bf16_1k(w2fr[nt], pkv, lacc0, 0, 0, 0);
        }
        f32x4 b2v = *reinterpret_cast<const f32x4*>(&sm.b2s[h][q*4]);
        lgt[h][mt] = lacc0 + lacc1 + b2v;   // row = g = q*4+r, col = token = lg
      }
    }

    // ---- epilogue tile s (fused log-domain form) ----
#pragma unroll
    for (int mt = 0; mt < 2; ++mt) {
      long tok = wbase + s*32 + mt*16 + lg;
      float d  = dpre[mt];
      bool  mk = (mpre[mt] != 0) && (d <= 8.0f);
      f32x4 LP = lgt[0][mt], LS = lgt[1][mt], LM = lgt[2][mt];

      float vm = v0 ? LP[0] : -INFINITY;
      if (v1) vm = fmaxf(vm, LP[1]);
      if (v2) vm = fmaxf(vm, LP[2]);
      if (v3) vm = fmaxf(vm, LP[3]);
      vm = fmaxf(vm, __shfl_xor(vm, 16));
      vm = fmaxf(vm, __shfl_xor(vm, 32));
      float e0 = v0 ? __expf(LP[0]-vm) : 0.f;
      float e1 = v1 ? __expf(LP[1]-vm) : 0.f;
      float e2 = v2 ? __expf(LP[2]-vm) : 0.f;
      float e3 = v3 ? __expf(LP[3]-vm) : 0.f;
      float ssum = e0+e1+e2+e3;
      ssum += __shfl_xor(ssum, 16);
      ssum += __shfl_xor(ssum, 32);
      float lss = __logf(ssum);
      float inv = 1.0f / ssum;
      float pi[4] = {e0*inv, e1*inv, e2*inv, e3*inv};

      float sg[4], mu[4], ll[4];
#pragma unroll
      for (int r = 0; r < 4; ++r) {
        sg[r] = (LS[r] > 0.f) ? (LS[r] + 1.4f) : (__expf(LS[r]) + 0.4f);
        mu[r] = (LM[r] > 0.f) ? (LM[r] + 1.0f) : __expf(LM[r]);
        float z = (d - mu[r]) / sg[r];
        ll[r] = -0.5f*z*z - __logf(sg[r]) - HLOG2PI;
      }

      if (q*4 < G_) {
        size_t o = (size_t)tok*G_ + q*4;
        *reinterpret_cast<float2*>(&out_pi[o]) = make_float2(pi[0], pi[1]);
        *reinterpret_cast<float2*>(&out_mu[o]) = make_float2(mu[0], mu[1]);
        *reinterpret_cast<float2*>(&out_sg[o]) = make_float2(sg[0], sg[1]);
        if (q*4+2 < G_) {
          *reinterpret_cast<float2*>(&out_pi[o+2]) = make_float2(pi[2], pi[3]);
          *reinterpret_cast<float2*>(&out_mu[o+2]) = make_float2(mu[2], mu[3]);
          *reinterpret_cast<float2*>(&out_sg[o+2]) = make_float2(sg[2], sg[3]);
        }
      }

      // a_g = log(pi_g) + ll_g = (LP - vm - lss) + ll   (eps-term negligible)
      float base = -vm - lss;
      float a0 = v0 ? (LP[0] + base + ll[0]) : -INFINITY;
      float a1x= v1 ? (LP[1] + base + ll[1]) : -INFINITY;
      float a2 = v2 ? (LP[2] + base + ll[2]) : -INFINITY;
      float a3 = v3 ? (LP[3] + base + ll[3]) : -INFINITY;
      float m2 = fmaxf(fmaxf(a0,a1x), fmaxf(a2,a3));
      m2 = fmaxf(m2, __shfl_xor(m2, 16));
      m2 = fmaxf(m2, __shfl_xor(m2, 32));
      float s2 = (v0?__expf(a0-m2):0.f) + (v1?__expf(a1x-m2):0.f)
               + (v2?__expf(a2-m2):0.f) + (v3?__expf(a3-m2):0.f);
      s2 += __shfl_xor(s2, 16);
      s2 += __shfl_xor(s2, 32);
      float closs = -(m2 + __logf(s2));
      // prob = sum(exp(a)) = s2 * exp(m2)
      float prob = s2 * __expf(m2) / (d*d + 1e-10f);

      if (lane < 16 && mk) { accP += prob; accL += closs; accC += 1.f; }
    }

    // ---- convert next tile ----
    if (s + 1 < NITER) {
#pragma unroll
      for (int mt = 0; mt < 2; ++mt) {
#pragma unroll
        for (int c = 0; c < 4; ++c) {
          float4 lo = fv[mt][2*c], hi = fv[mt][2*c+1];
          bf16x8 a;
          a[0]=f2bf(lo.x); a[1]=f2bf(lo.y); a[2]=f2bf(lo.z); a[3]=f2bf(lo.w);
          a[4]=f2bf(hi.x); a[5]=f2bf(hi.y); a[6]=f2bf(hi.z); a[7]=f2bf(hi.w);
          a1[mt][c] = a;
        }
        dpre[mt] = dnx[mt]; mpre[mt] = mnx[mt];
      }
    }
  }

  // ---- block reduce; block lies entirely in one batch b ----
  accP += __shfl_xor(accP, 1); accP += __shfl_xor(accP, 2);
  accP += __shfl_xor(accP, 4); accP += __shfl_xor(accP, 8);
  accL += __shfl_xor(accL, 1); accL += __shfl_xor(accL, 2);
  accL += __shfl_xor(accL, 4); accL += __shfl_xor(accL, 8);
  accC += __shfl_xor(accC, 1); accC += __shfl_xor(accC, 2);
  accC += __shfl_xor(accC, 4); accC += __shfl_xor(accC, 8);
  if (lane == 0) { sm.red[wave][0] = accP; sm.red[wave][1] = accL; sm.red[wave][2] = accC; }
  __syncthreads();
  if (tid == 0) {
    float sP = 0.f, sL = 0.f, sC = 0.f;
    for (int w = 0; w < WAVES; ++w) { sP += sm.red[w][0]; sL += sm.red[w][1]; sC += sm.red[w][2]; }
    int b = blockIdx.x >> 3;   // 8 blocks per batch
    atomicAdd(&out_score[b], sP);
    atomicAdd(&ws[0], sL);
    atomicAdd(&ws[1], sC);
  }
}

extern "C" void kernel_launch(void* const* d_in, const int* in_sizes, int n_in,
                              void* d_out, int out_size, void* d_ws, size_t ws_size,
                              hipStream_t stream) {
  const float* feat = (const float*)d_in[0];
  const float* dist = (const float*)d_in[1];
  const int* dmask = (const int*)d_in[2];
  float* out = (float*)d_out;
  float* ws  = (float*)d_ws;

  hipLaunchKernelGGL(init_kernel, dim3(1), dim3(64), 0, stream, out, ws);

  bool prep_ok = (ws_size >= (size_t)(WS_IMG_OFF + IMG_INSTS*1024));
  if (prep_ok) {
    short* img = (short*)((char*)d_ws + WS_IMG_OFF);
    hipLaunchKernelGGL(prep_kernel, dim3(116), dim3(256), 0, stream,
        (const float*)d_in[3],  (const float*)d_in[4],  (const float*)d_in[5],  (const float*)d_in[6],
        (const float*)d_in[7],  (const float*)d_in[8],  (const float*)d_in[9],  (const float*)d_in[10],
        (const float*)d_in[11], (const float*)d_in[12], (const float*)d_in[13], (const float*)d_in[14],
        img);
    hipLaunchKernelGGL((rtm_main<1>), dim3(TOKS/TPB), dim3(THREADS), 0, stream,
        feat, dist, dmask, (const float*)img,
        (const float*)d_in[3],  (const float*)d_in[4],  (const float*)d_in[5],  (const float*)d_in[6],
        (const float*)d_in[7],  (const float*)d_in[8],  (const float*)d_in[9],  (const float*)d_in[10],
        (const float*)d_in[11], (const float*)d_in[12], (const float*)d_in[13], (const float*)d_in[14],
        out, ws);
  } else {
    hipLaunchKernelGGL((rtm_main<0>), dim3(TOKS/TPB), dim3(THREADS), 0, stream,
        feat, dist, dmask, (const float*)nullptr,
        (const float*)d_in[3],  (const float*)d_in[4],  (const float*)d_in[5],  (const float*)d_in[6],
        (const float*)d_in[7],  (const float*)d_in[8],  (const float*)d_in[9],  (const float*)d_in[10],
        (const float*)d_in[11], (const float*)d_in[12], (const float*)d_in[13], (const float*)d_in[14],
        out, ws);
  }

  hipLaunchKernelGGL(fin_kernel, dim3(1), dim3(64), 0, stream, out, ws);
}